// Round 20
// baseline (208.519 us; speedup 1.0000x reference)
//
#include <hip/hip_runtime.h>
#include <hip/hip_bf16.h>

constexpr int D  = 128;
constexpr int H  = 8;
constexpr int DH = 16;
constexpr int NB  = 16;  // nodes per MFMA tile / type-bucket alignment
constexpr int NBO = 16;  // nodes per k_out tile
constexpr int T  = 3;

typedef __attribute__((ext_vector_type(8))) short bf16x8;
typedef __attribute__((ext_vector_type(4))) float f32x4;

__device__ inline unsigned short f2bf(float f) {  // fp32 -> bf16 bits (RNE)
  unsigned u = __float_as_uint(f);
  unsigned r = u + 0x7fffu + ((u >> 16) & 1u);
  return (unsigned short)(r >> 16);
}

// ---------- fused prep. Block roles (latency-bound tails FIRST):
//   blk 0: FiLM;  [1,10): weight prep (m=0: cast Wk; m=1: Wq'=Wq·BD(ra^T)·rp/4;
//   m=2: Wv'=Wv·BD(rm)) -> bf16 [col][k];  [10,10+BE): edge count+hist;
//   [10+BE,...): cast x ----------
__global__ void k_prep(const int* __restrict__ dst, const int* __restrict__ ntype,
                       int* __restrict__ deg, int* __restrict__ tcnt, int N, int E,
                       const float* __restrict__ x, unsigned short* __restrict__ xb,
                       int n8,
                       const float* __restrict__ Wk, const float* __restrict__ Wq,
                       const float* __restrict__ Wv, unsigned short* __restrict__ Wt,
                       const float* __restrict__ ra_, const float* __restrict__ rm_,
                       const float* __restrict__ rp,
                       const float* __restrict__ gc, const float* __restrict__ fw,
                       const float* __restrict__ fb, float* __restrict__ gb, int C,
                       int BE) {
  int blk = blockIdx.x, tid = threadIdx.x;
  if (blk == 0) {  // FiLM: gb[0:128]=gamma, gb[128:256]=beta (256 threads)
    float a0 = 0.f, a1 = 0.f, a2 = 0.f, a3 = 0.f;
    int c = 0;
    for (; c + 4 <= C; c += 4) {
      a0 += gc[c] * fw[c * 256 + tid];
      a1 += gc[c + 1] * fw[(c + 1) * 256 + tid];
      a2 += gc[c + 2] * fw[(c + 2) * 256 + tid];
      a3 += gc[c + 3] * fw[(c + 3) * 256 + tid];
    }
    float acc = fb[tid] + (a0 + a1) + (a2 + a3);
    for (; c < C; ++c) acc += gc[c] * fw[c * 256 + tid];
    gb[tid] = acc;
    return;
  }
  if (blk < 10) {  // weight prep -> Wt[m][t][col][k] bf16, coalesced writes
    int b2 = blk - 1;
    int m = b2 / T, t = b2 % T;
    unsigned short* o = Wt + ((size_t)m * T + t) * (D * D);
    if (m == 0) {
      const float* W = Wk + (size_t)t * (D * D);
      for (int idx = tid; idx < D * D; idx += 256) {
        int col = idx >> 7, d = idx & 127;  // consecutive tid -> consecutive d
        o[(size_t)col * D + d] = f2bf(W[(size_t)d * D + col]);
      }
    } else {
      const float* W = (m == 1 ? Wq : Wv) + (size_t)t * (D * D);
      for (int idx = tid; idx < D * D; idx += 256) {
        int col = idx >> 7, c = idx & 127;  // c = k index, coalesced writes
        int h = col >> 4, dd = col & 15;
        const float* wrow = W + (size_t)c * D + h * 16;
        float s = 0.f;
        if (m == 1) {
          const float* rar = ra_ + h * 256 + dd * 16;
#pragma unroll
          for (int z = 0; z < 16; ++z) s += wrow[z] * rar[z];
          s *= rp[h] * 0.25f;
        } else {
          const float* rmr = rm_ + h * 256 + dd;  // stride 16
#pragma unroll
          for (int z = 0; z < 16; ++z) s += wrow[z] * rmr[z * 16];
        }
        o[(size_t)col * D + c] = f2bf(s);
      }
    }
    return;
  }
  if (blk < 10 + BE) {  // edge in-degree count + node type histogram
    int i = (blk - 10) * 256 + tid;
    if (i < E) atomicAdd(deg + dst[i], 1);
    int t = (i < N) ? ntype[i] : -1;
    int lane = tid & 63;
#pragma unroll
    for (int tt = 0; tt < T; ++tt) {
      unsigned long long mask = __ballot(t == tt);
      int cnt = __popcll(mask);
      if (cnt > 0 && lane == (__ffsll((long long)mask) - 1))
        atomicAdd(tcnt + tt, cnt);
    }
    return;
  }
  // cast x -> bf16, 8 elems/thread
  int i = (blk - 10 - BE) * 256 + tid;
  if (i >= n8) return;
  const float4* p = (const float4*)(x + (size_t)i * 8);
  float4 a = p[0], b = p[1];
  ushort4 o0 = {f2bf(a.x), f2bf(a.y), f2bf(a.z), f2bf(a.w)};
  ushort4 o1 = {f2bf(b.x), f2bf(b.y), f2bf(b.z), f2bf(b.w)};
  ushort4* q = (ushort4*)(xb + (size_t)i * 8);
  q[0] = o0;
  q[1] = o1;
}

// ---------- exclusive prefix sum over deg -> off[0..N]; also toff from tcnt ----------
__global__ void k_scan(const int* __restrict__ deg, int* __restrict__ off,
                       const int* __restrict__ tcnt, int* __restrict__ toff,
                       int N, int E) {
  __shared__ int wsum[16];
  __shared__ int base_s;
  int tid = threadIdx.x;          // 0..1023
  int lane = tid & 63, w = tid >> 6;
  if (tid == 0) {
    base_s = 0;
    toff[0] = 0;
    for (int t = 0; t < T; ++t) toff[t + 1] = toff[t] + ((tcnt[t] + NB - 1) / NB) * NB;
  }
  __syncthreads();
  for (int start = 0; start < N; start += 1024) {
    int i = start + tid;
    int v = (i < N) ? deg[i] : 0;
    int x = v;
#pragma unroll
    for (int o = 1; o < 64; o <<= 1) {
      int y = __shfl_up(x, o);
      if (lane >= o) x += y;
    }
    if (lane == 63) wsum[w] = x;
    __syncthreads();
    if (w == 0 && lane < 16) {
      int s = wsum[lane];
#pragma unroll
      for (int o = 1; o < 16; o <<= 1) {
        int y = __shfl_up(s, o);
        if (lane >= o) s += y;
      }
      wsum[lane] = s;
    }
    __syncthreads();
    int waveoff = (w > 0) ? wsum[w - 1] : 0;
    if (i < N) off[i] = base_s + waveoff + x - v;
    __syncthreads();
    if (tid == 0) base_s += wsum[15];
    __syncthreads();
  }
  if (tid == 0) off[N] = E;
}

// ---------- scatter: edges -> CSR src values; nodes -> type buckets ----------
__global__ void k_scatter(const int* __restrict__ dst, const int* __restrict__ src,
                          const int* __restrict__ ntype,
                          const int* __restrict__ off, const int* __restrict__ toff,
                          int* __restrict__ cursor, int* __restrict__ tcur,
                          int* __restrict__ esrc, int* __restrict__ pnid, int N, int E) {
  int i = blockIdx.x * blockDim.x + threadIdx.x;
  if (i < E) {
    int d = dst[i];
    int pos = atomicAdd(cursor + d, 1);
    esrc[off[d] + pos] = src[i];
  }
  int t = (i < N) ? ntype[i] : -1;
  int lane = threadIdx.x & 63;
#pragma unroll
  for (int tt = 0; tt < T; ++tt) {
    unsigned long long mask = __ballot(t == tt);
    int cnt = __popcll(mask);
    if (cnt == 0) continue;
    int leader = __ffsll((long long)mask) - 1;
    int base = 0;
    if (lane == leader) base = atomicAdd(tcur + tt, cnt);
    base = __shfl(base, leader);
    if (t == tt) {
      int rank = __popcll(mask & ((1ull << lane) - 1ull));
      pnid[toff[tt] + base + rank] = i;
    }
  }
}

// ---------- fused MFMA projection: 16 nodes x 128 out x 3 matrices (k, qt, mt).
//            One A-fragment gather feeds 3 GEMMs; head transforms pre-folded
//            into Wq'/Wv'. 256 thr = 4 waves, wave owns 32 output cols.
//            A-frag: lane l elem i = A[l&15][(l>>4)*8+i]  (row-major)
//            B-frag: lane l elem i = B[(l>>4)*8+i][l&15]  (Wt col-major [c][k])
//            D: col = lane&15, row = (lane>>4)*4+reg  [verified r10/r14] ----------
__global__ void __launch_bounds__(256)
k_proj_f(const unsigned short* __restrict__ xb, const int* __restrict__ pnid,
         const int* __restrict__ ntype, const unsigned short* __restrict__ Wt,
         unsigned int* __restrict__ kmpk, float* __restrict__ oqt) {
  int b = blockIdx.x;
  int tid = threadIdx.x;
  int w = tid >> 6, l = tid & 63;
  __shared__ int nid_s[NB];
  if (tid < NB) nid_s[tid] = pnid[b * NB + tid];
  __syncthreads();
  int tfirst = -1;
#pragma unroll
  for (int nn = 0; nn < NB; ++nn) if (tfirst < 0 && nid_s[nn] >= 0) tfirst = ntype[nid_s[nn]];
  if (tfirst < 0) return;  // fully-padded block

  int arow = l & 15, kg = l >> 4;
  int anid = nid_s[arow];
  if (anid < 0) anid = 0;  // clamp: garbage rows never written back
  const unsigned short* abase = xb + (size_t)anid * D + kg * 8;
  int col0 = w * 32 + (l & 15);
  size_t coff = (size_t)col0 * D + kg * 8;
  const unsigned short* wk = Wt + ((size_t)0 * T + tfirst) * (D * D) + coff;
  const unsigned short* wq = Wt + ((size_t)1 * T + tfirst) * (D * D) + coff;
  const unsigned short* wv = Wt + ((size_t)2 * T + tfirst) * (D * D) + coff;
  f32x4 aK0 = {0.f, 0.f, 0.f, 0.f}, aK1 = aK0;
  f32x4 aQ0 = aK0, aQ1 = aK0, aV0 = aK0, aV1 = aK0;
#pragma unroll
  for (int ks = 0; ks < 4; ++ks) {
    bf16x8 af  = *(const bf16x8*)(abase + ks * 32);
    bf16x8 k0  = *(const bf16x8*)(wk + ks * 32);
    bf16x8 k1  = *(const bf16x8*)(wk + (size_t)16 * D + ks * 32);
    bf16x8 q0  = *(const bf16x8*)(wq + ks * 32);
    bf16x8 q1  = *(const bf16x8*)(wq + (size_t)16 * D + ks * 32);
    bf16x8 v0  = *(const bf16x8*)(wv + ks * 32);
    bf16x8 v1  = *(const bf16x8*)(wv + (size_t)16 * D + ks * 32);
    aK0 = __builtin_amdgcn_mfma_f32_16x16x32_bf16(af, k0, aK0, 0, 0, 0);
    aK1 = __builtin_amdgcn_mfma_f32_16x16x32_bf16(af, k1, aK1, 0, 0, 0);
    aQ0 = __builtin_amdgcn_mfma_f32_16x16x32_bf16(af, q0, aQ0, 0, 0, 0);
    aQ1 = __builtin_amdgcn_mfma_f32_16x16x32_bf16(af, q1, aQ1, 0, 0, 0);
    aV0 = __builtin_amdgcn_mfma_f32_16x16x32_bf16(af, v0, aV0, 0, 0, 0);
    aV1 = __builtin_amdgcn_mfma_f32_16x16x32_bf16(af, v1, aV1, 0, 0, 0);
  }

  int o = l & 15, kg4 = (l >> 4) * 4;
#pragma unroll
  for (int ct = 0; ct < 2; ++ct) {
    f32x4 aK = ct ? aK1 : aK0;
    f32x4 aQ = ct ? aQ1 : aQ0;
    f32x4 aV = ct ? aV1 : aV0;
    int col = w * 32 + ct * 16 + o;
#pragma unroll
    for (int r = 0; r < 4; ++r) {
      int nid = nid_s[kg4 + r];
      if (nid >= 0) {
        kmpk[(size_t)nid * D + col] =
            ((unsigned)f2bf(aV[r]) << 16) | (unsigned)f2bf(aK[r]);
        oqt[(size_t)nid * D + col] = aQ[r];
      }
    }
  }
}

// ---------- per-node softmax aggregation, no max-shift (|a| << 1, exp safe),
//            4-way unrolled, fully pipelined accumulation ----------
__global__ void k_agg(const int* __restrict__ esrc, const int* __restrict__ off,
                      const unsigned int* __restrict__ kmpk,
                      const float* __restrict__ qt,
                      float* __restrict__ hagg, int N) {
  int n = blockIdx.x;
  int j = threadIdx.x;  // 0..127
  float qv = qt[(size_t)n * D + j];
  int i0 = off[n], i1 = off[n + 1];
  float ssum = 0.f, acc = 0.f;
  int i = i0;
  for (; i + 4 <= i1; i += 4) {
    int s0 = esrc[i], s1 = esrc[i + 1], s2 = esrc[i + 2], s3 = esrc[i + 3];
    unsigned p0 = kmpk[(size_t)s0 * D + j];
    unsigned p1 = kmpk[(size_t)s1 * D + j];
    unsigned p2 = kmpk[(size_t)s2 * D + j];
    unsigned p3 = kmpk[(size_t)s3 * D + j];
    float kv0 = __uint_as_float(p0 << 16), mv0 = __uint_as_float(p0 & 0xffff0000u);
    float kv1 = __uint_as_float(p1 << 16), mv1 = __uint_as_float(p1 & 0xffff0000u);
    float kv2 = __uint_as_float(p2 << 16), mv2 = __uint_as_float(p2 & 0xffff0000u);
    float kv3 = __uint_as_float(p3 << 16), mv3 = __uint_as_float(p3 & 0xffff0000u);
    float a0 = kv0 * qv, a1 = kv1 * qv, a2 = kv2 * qv, a3 = kv3 * qv;
#pragma unroll
    for (int o = 8; o >= 1; o >>= 1) {
      a0 += __shfl_xor(a0, o);
      a1 += __shfl_xor(a1, o);
      a2 += __shfl_xor(a2, o);
      a3 += __shfl_xor(a3, o);
    }
    float w0 = __expf(a0), w1 = __expf(a1), w2 = __expf(a2), w3 = __expf(a3);
    ssum += (w0 + w1) + (w2 + w3);
    acc += (w0 * mv0 + w1 * mv1) + (w2 * mv2 + w3 * mv3);
  }
  for (; i < i1; ++i) {
    int sn = esrc[i];
    unsigned p = kmpk[(size_t)sn * D + j];
    float kv = __uint_as_float(p << 16), mv = __uint_as_float(p & 0xffff0000u);
    float a = kv * qv;
#pragma unroll
    for (int o = 8; o >= 1; o >>= 1) a += __shfl_xor(a, o);
    float wgt = __expf(a);
    ssum += wgt;
    acc += wgt * mv;
  }
  hagg[(size_t)n * D + j] = (ssum > 0.f) ? acc / ssum : 0.f;
}

// ---------- fp32 Wa GEMM, 16 nodes/block, 512 thr (4 node-groups x 4 nodes),
//            unroll-4 pipeline + x prefetch; skip/LN/residual/FiLM epilogue ----------
__global__ void __launch_bounds__(512)
k_out(const float* __restrict__ hagg, const int* __restrict__ pnid,
      const int* __restrict__ ntype, const float* __restrict__ Wa,
      const float* __restrict__ x, const float* __restrict__ skip,
      const float* __restrict__ ln_g, const float* __restrict__ ln_b,
      const float* __restrict__ gb, float* __restrict__ out) {
  int b = blockIdx.x, tid = threadIdx.x;
  int j = tid & 127, g = tid >> 7;  // g in {0..3}: nodes g*4 .. g*4+3
  __shared__ __align__(16) float hs[NBO][D];
  __shared__ int nid_s[NBO];
  __shared__ float red[8][4][2];  // [wave][local nn][s1,s2]
  if (tid < NBO) nid_s[tid] = pnid[b * NBO + tid];
  __syncthreads();
  for (int idx = tid; idx < NBO * D; idx += 512) {
    int nn = idx >> 7, col = idx & 127;
    int nid = nid_s[nn];
    hs[nn][col] = (nid >= 0) ? hagg[(size_t)nid * D + col] : 0.f;
  }
  __syncthreads();
  int tfirst = -1;
#pragma unroll
  for (int nn = 0; nn < NBO; ++nn) if (tfirst < 0 && nid_s[nn] >= 0) tfirst = ntype[nid_s[nn]];
  if (tfirst < 0) return;
  // prefetch epilogue x values: latency hides under the GEMM below
  float xpre[4];
#pragma unroll
  for (int nn = 0; nn < 4; ++nn) {
    int nid = nid_s[g * 4 + nn];
    xpre[nn] = (nid >= 0) ? x[(size_t)nid * D + j] : 0.f;
  }
  const float* wp = Wa + (size_t)tfirst * (D * D) + j;  // coalesced across j
  float acc[4];
#pragma unroll
  for (int nn = 0; nn < 4; ++nn) acc[nn] = 0.f;
#pragma unroll 4
  for (int d = 0; d < D; d += 4) {
    float w0 = wp[(size_t)d * D];
    float w1 = wp[(size_t)(d + 1) * D];
    float w2 = wp[(size_t)(d + 2) * D];
    float w3 = wp[(size_t)(d + 3) * D];
#pragma unroll
    for (int nn = 0; nn < 4; ++nn) {
      float4 h4 = *(const float4*)(&hs[g * 4 + nn][d]);  // ds_read_b128
      acc[nn] = fmaf(h4.x, w0, acc[nn]);
      acc[nn] = fmaf(h4.y, w1, acc[nn]);
      acc[nn] = fmaf(h4.z, w2, acc[nn]);
      acc[nn] = fmaf(h4.w, w3, acc[nn]);
    }
  }
  float alpha = 1.f / (1.f + __expf(-skip[tfirst]));
  int w = tid >> 6;  // 0..7
  float hv[4];
#pragma unroll
  for (int nn = 0; nn < 4; ++nn) {
    int nid = nid_s[g * 4 + nn];
    hv[nn] = (nid >= 0) ? (acc[nn] * alpha + xpre[nn] * (1.f - alpha)) : 0.f;
    float s1 = hv[nn], s2 = hv[nn] * hv[nn];
#pragma unroll
    for (int o = 1; o < 64; o <<= 1) {
      s1 += __shfl_xor(s1, o);
      s2 += __shfl_xor(s2, o);
    }
    if ((tid & 63) == 0) { red[w][nn][0] = s1; red[w][nn][1] = s2; }
  }
  __syncthreads();
  float gj = ln_g[j], bj = ln_b[j], gmj = gb[j], gbj = gb[D + j];
#pragma unroll
  for (int nn = 0; nn < 4; ++nn) {
    int nid = nid_s[g * 4 + nn];
    if (nid < 0) continue;
    float mu = (red[2 * g][nn][0] + red[2 * g + 1][nn][0]) * (1.f / D);
    float m2 = (red[2 * g][nn][1] + red[2 * g + 1][nn][1]) * (1.f / D);
    float var = m2 - mu * mu;
    float y = (hv[nn] - mu) * rsqrtf(var + 1e-5f) * gj + bj + xpre[nn];
    out[(size_t)nid * D + j] = gmj * y + gbj;
  }
}

extern "C" void kernel_launch(void* const* d_in, const int* in_sizes, int n_in,
                              void* d_out, int out_size, void* d_ws, size_t ws_size,
                              hipStream_t stream) {
  const float* x       = (const float*)d_in[0];
  const float* gc      = (const float*)d_in[1];
  const float* Wk      = (const float*)d_in[2];
  const float* Wq      = (const float*)d_in[3];
  const float* Wv      = (const float*)d_in[4];
  const float* rel_att = (const float*)d_in[5];
  const float* rel_msg = (const float*)d_in[6];
  const float* rel_pri = (const float*)d_in[7];
  const float* Wa      = (const float*)d_in[8];
  const float* skip    = (const float*)d_in[9];
  const float* ln_g    = (const float*)d_in[10];
  const float* ln_b    = (const float*)d_in[11];
  const float* fw      = (const float*)d_in[12];
  const float* fb      = (const float*)d_in[13];
  const int* ntype     = (const int*)d_in[14];
  const int* src       = (const int*)d_in[15];
  const int* dst       = (const int*)d_in[16];
  float* out = (float*)d_out;

  int N = in_sizes[0] / D;
  int C = in_sizes[1];
  int E = in_sizes[15];

  int gridP = (N + NB - 1) / NB + T;  // upper bound on padded 16-node tiles
  int P = gridP * NB;                 // padded node-list size
  int gridO = P / NBO;                // 16-node tiles

  float* ws = (float*)d_ws;
  size_t nD = (size_t)N * D;
  float* wqt   = ws;                                 // N*128 fp32 qt (scaled)
  float* whagg = wqt + nD;                           // N*128 fp32 h_agg
  float* wgb   = whagg + nD;                         // 256 gamma|beta
  unsigned int*   kmpk = (unsigned int*)(wgb + 256); // N*128 packed {k,mt} bf16
  unsigned short* xb   = (unsigned short*)(kmpk + nD);  // N*128 bf16 x
  unsigned short* Wt   = xb + nD;                    // 3*3*128*128 bf16 col-major
  int* deg    = (int*)(Wt + 9 * D * D);  // N  (zeroed: deg,cursor,tcnt,tcur)
  int* cursor = deg + N;                 // N
  int* tcnt   = cursor + N;              // T
  int* tcur   = tcnt + T;                // T
  int* off    = tcur + T;                // N+1
  int* toff   = off + N + 1;             // T+1
  int* esrc   = toff + T + 1;            // E  (CSR-ordered src values)
  int* pnid   = esrc + E;                // P  (memset 0xFF -> -1)

  (void)hipMemsetAsync(deg, 0, (size_t)(2 * N + 2 * T) * sizeof(int), stream);
  (void)hipMemsetAsync(pnid, 0xFF, (size_t)P * sizeof(int), stream);

  int mNE = (E > N) ? E : N;
  int n8 = (int)(nD / 8);
  int BE = (mNE + 255) / 256;
  int BX = (n8 + 255) / 256;
  k_prep<<<10 + BE + BX, 256, 0, stream>>>(dst, ntype, deg, tcnt, N, E,
                                           x, xb, n8, Wk, Wq, Wv, Wt,
                                           rel_att, rel_msg, rel_pri,
                                           gc, fw, fb, wgb, C, BE);
  k_scan<<<1, 1024, 0, stream>>>(deg, off, tcnt, toff, N, E);
  k_scatter<<<(mNE + 255) / 256, 256, 0, stream>>>(dst, src, ntype, off, toff,
                                                   cursor, tcur, esrc, pnid, N, E);
  k_proj_f<<<gridP, 256, 0, stream>>>(xb, pnid, ntype, Wt, kmpk, wqt);
  k_agg<<<N, D, 0, stream>>>(esrc, off, kmpk, wqt, whagg, N);
  k_out<<<gridO, 512, 0, stream>>>(whagg, pnid, ntype, Wa, x, skip, ln_g, ln_b,
                                   wgb, out);
}

// Round 21
// 172.978 us; speedup vs baseline: 1.2055x; 1.2055x over previous
//
#include <hip/hip_runtime.h>
#include <hip/hip_bf16.h>

constexpr int D  = 128;
constexpr int H  = 8;
constexpr int DH = 16;
constexpr int NB  = 16;  // nodes per MFMA tile / type-bucket alignment
constexpr int NBO = 16;  // nodes per k_out tile
constexpr int T  = 3;

typedef __attribute__((ext_vector_type(8))) short bf16x8;
typedef __attribute__((ext_vector_type(4))) float f32x4;

__device__ inline unsigned short f2bf(float f) {  // fp32 -> bf16 bits (RNE)
  unsigned u = __float_as_uint(f);
  unsigned r = u + 0x7fffu + ((u >> 16) & 1u);
  return (unsigned short)(r >> 16);
}

// ---------- fused prep. Block roles:
//   blk 0: FiLM
//   [1, 73): weight prep, 72 chunk-blocks = 9 matrices x 8 col-chunks (16 cols
//            = one head). m=0: cast Wk; m=1: Wq' = Wq·BD(ra^T)·rp/4;
//            m=2: Wv' = Wv·BD(rm). Coefs cached in LDS; bit-identical to r20.
//   [73, 73+BE): edge count + type hist, 4 edges/thread
//   [73+BE, ...): cast x -> bf16, 8 elems/thread ----------
__global__ void k_prep(const int* __restrict__ dst, const int* __restrict__ ntype,
                       int* __restrict__ deg, int* __restrict__ tcnt, int N, int E,
                       const float* __restrict__ x, unsigned short* __restrict__ xb,
                       int n8,
                       const float* __restrict__ Wk, const float* __restrict__ Wq,
                       const float* __restrict__ Wv, unsigned short* __restrict__ Wt,
                       const float* __restrict__ ra_, const float* __restrict__ rm_,
                       const float* __restrict__ rp,
                       const float* __restrict__ gc, const float* __restrict__ fw,
                       const float* __restrict__ fb, float* __restrict__ gb, int C,
                       int BE) {
  int blk = blockIdx.x, tid = threadIdx.x;
  if (blk == 0) {  // FiLM: gb[0:128]=gamma, gb[128:256]=beta (256 threads)
    float a0 = 0.f, a1 = 0.f, a2 = 0.f, a3 = 0.f;
    int c = 0;
    for (; c + 4 <= C; c += 4) {
      a0 += gc[c] * fw[c * 256 + tid];
      a1 += gc[c + 1] * fw[(c + 1) * 256 + tid];
      a2 += gc[c + 2] * fw[(c + 2) * 256 + tid];
      a3 += gc[c + 3] * fw[(c + 3) * 256 + tid];
    }
    float acc = fb[tid] + (a0 + a1) + (a2 + a3);
    for (; c < C; ++c) acc += gc[c] * fw[c * 256 + tid];
    gb[tid] = acc;
    return;
  }
  if (blk < 73) {  // weight prep chunk
    int b2 = blk - 1;              // 0..71
    int mt = b2 >> 3, chunk = b2 & 7;
    int m = mt / T, t = mt % T;
    unsigned short* o = Wt + ((size_t)m * T + t) * (D * D);
    if (m == 0) {
      const float* W = Wk + (size_t)t * (D * D);
#pragma unroll
      for (int k2 = 0; k2 < 8; ++k2) {
        int idx = k2 * 256 + tid;        // 0..2047
        int d = idx & 127, colL = idx >> 7;
        int col = chunk * 16 + colL;
        o[(size_t)col * D + d] = f2bf(W[(size_t)d * D + col]);
      }
      return;
    }
    __shared__ float cf[256];  // cf[dd*16+z]
    int h = chunk;
    if (m == 1) cf[tid] = ra_[h * 256 + tid];
    else        cf[tid] = rm_[h * 256 + (tid & 15) * 16 + (tid >> 4)];
    float scale = (m == 1) ? rp[h] * 0.25f : 1.f;
    __syncthreads();
    const float* W = (m == 1 ? Wq : Wv) + (size_t)t * (D * D);
#pragma unroll
    for (int k2 = 0; k2 < 8; ++k2) {
      int idx = k2 * 256 + tid;
      int c = idx & 127, colL = idx >> 7;   // consecutive tid -> consecutive c
      int col = chunk * 16 + colL, dd = colL;
      const float* wrow = W + (size_t)c * D + h * 16;
      float s = 0.f;
#pragma unroll
      for (int z = 0; z < 16; ++z) s += wrow[z] * cf[dd * 16 + z];
      o[(size_t)col * D + c] = f2bf(s * scale);
    }
    return;
  }
  if (blk < 73 + BE) {  // edge in-degree count + node type histogram (4/thread)
    int base = (blk - 73) * 1024;
    int lane = tid & 63;
#pragma unroll
    for (int k2 = 0; k2 < 4; ++k2) {
      int i = base + k2 * 256 + tid;
      if (i < E) atomicAdd(deg + dst[i], 1);
      int t = (i < N) ? ntype[i] : -1;
#pragma unroll
      for (int tt = 0; tt < T; ++tt) {
        unsigned long long mask = __ballot(t == tt);
        int cnt = __popcll(mask);
        if (cnt > 0 && lane == (__ffsll((long long)mask) - 1))
          atomicAdd(tcnt + tt, cnt);
      }
    }
    return;
  }
  // cast x -> bf16, 8 elems/thread
  int i = (blk - 73 - BE) * 256 + tid;
  if (i >= n8) return;
  const float4* p = (const float4*)(x + (size_t)i * 8);
  float4 a = p[0], b = p[1];
  ushort4 o0 = {f2bf(a.x), f2bf(a.y), f2bf(a.z), f2bf(a.w)};
  ushort4 o1 = {f2bf(b.x), f2bf(b.y), f2bf(b.z), f2bf(b.w)};
  ushort4* q = (ushort4*)(xb + (size_t)i * 8);
  q[0] = o0;
  q[1] = o1;
}

// ---------- exclusive prefix sum over deg -> off[0..N]; also toff from tcnt ----------
__global__ void k_scan(const int* __restrict__ deg, int* __restrict__ off,
                       const int* __restrict__ tcnt, int* __restrict__ toff,
                       int N, int E) {
  __shared__ int wsum[16];
  __shared__ int base_s;
  int tid = threadIdx.x;          // 0..1023
  int lane = tid & 63, w = tid >> 6;
  if (tid == 0) {
    base_s = 0;
    toff[0] = 0;
    for (int t = 0; t < T; ++t) toff[t + 1] = toff[t] + ((tcnt[t] + NB - 1) / NB) * NB;
  }
  __syncthreads();
  for (int start = 0; start < N; start += 1024) {
    int i = start + tid;
    int v = (i < N) ? deg[i] : 0;
    int x = v;
#pragma unroll
    for (int o = 1; o < 64; o <<= 1) {
      int y = __shfl_up(x, o);
      if (lane >= o) x += y;
    }
    if (lane == 63) wsum[w] = x;
    __syncthreads();
    if (w == 0 && lane < 16) {
      int s = wsum[lane];
#pragma unroll
      for (int o = 1; o < 16; o <<= 1) {
        int y = __shfl_up(s, o);
        if (lane >= o) s += y;
      }
      wsum[lane] = s;
    }
    __syncthreads();
    int waveoff = (w > 0) ? wsum[w - 1] : 0;
    if (i < N) off[i] = base_s + waveoff + x - v;
    __syncthreads();
    if (tid == 0) base_s += wsum[15];
    __syncthreads();
  }
  if (tid == 0) off[N] = E;
}

// ---------- scatter: edges -> CSR src values; nodes -> type buckets ----------
__global__ void k_scatter(const int* __restrict__ dst, const int* __restrict__ src,
                          const int* __restrict__ ntype,
                          const int* __restrict__ off, const int* __restrict__ toff,
                          int* __restrict__ cursor, int* __restrict__ tcur,
                          int* __restrict__ esrc, int* __restrict__ pnid, int N, int E) {
  int i = blockIdx.x * blockDim.x + threadIdx.x;
  if (i < E) {
    int d = dst[i];
    int pos = atomicAdd(cursor + d, 1);
    esrc[off[d] + pos] = src[i];
  }
  int t = (i < N) ? ntype[i] : -1;
  int lane = threadIdx.x & 63;
#pragma unroll
  for (int tt = 0; tt < T; ++tt) {
    unsigned long long mask = __ballot(t == tt);
    int cnt = __popcll(mask);
    if (cnt == 0) continue;
    int leader = __ffsll((long long)mask) - 1;
    int base = 0;
    if (lane == leader) base = atomicAdd(tcur + tt, cnt);
    base = __shfl(base, leader);
    if (t == tt) {
      int rank = __popcll(mask & ((1ull << lane) - 1ull));
      pnid[toff[tt] + base + rank] = i;
    }
  }
}

// ---------- fused MFMA projection: 16 nodes x 128 out x 3 matrices (k, qt, mt).
//            One A-fragment gather feeds 3 GEMMs; head transforms pre-folded
//            into Wq'/Wv'. 256 thr = 4 waves, wave owns 32 output cols.
//            A-frag: lane l elem i = A[l&15][(l>>4)*8+i]  (row-major)
//            B-frag: lane l elem i = B[(l>>4)*8+i][l&15]  (Wt col-major [c][k])
//            D: col = lane&15, row = (lane>>4)*4+reg  [verified r10/r14] ----------
__global__ void __launch_bounds__(256)
k_proj_f(const unsigned short* __restrict__ xb, const int* __restrict__ pnid,
         const int* __restrict__ ntype, const unsigned short* __restrict__ Wt,
         unsigned int* __restrict__ kmpk, float* __restrict__ oqt) {
  int b = blockIdx.x;
  int tid = threadIdx.x;
  int w = tid >> 6, l = tid & 63;
  __shared__ int nid_s[NB];
  if (tid < NB) nid_s[tid] = pnid[b * NB + tid];
  __syncthreads();
  int tfirst = -1;
#pragma unroll
  for (int nn = 0; nn < NB; ++nn) if (tfirst < 0 && nid_s[nn] >= 0) tfirst = ntype[nid_s[nn]];
  if (tfirst < 0) return;  // fully-padded block

  int arow = l & 15, kg = l >> 4;
  int anid = nid_s[arow];
  if (anid < 0) anid = 0;  // clamp: garbage rows never written back
  const unsigned short* abase = xb + (size_t)anid * D + kg * 8;
  int col0 = w * 32 + (l & 15);
  size_t coff = (size_t)col0 * D + kg * 8;
  const unsigned short* wk = Wt + ((size_t)0 * T + tfirst) * (D * D) + coff;
  const unsigned short* wq = Wt + ((size_t)1 * T + tfirst) * (D * D) + coff;
  const unsigned short* wv = Wt + ((size_t)2 * T + tfirst) * (D * D) + coff;
  f32x4 aK0 = {0.f, 0.f, 0.f, 0.f}, aK1 = aK0;
  f32x4 aQ0 = aK0, aQ1 = aK0, aV0 = aK0, aV1 = aK0;
#pragma unroll
  for (int ks = 0; ks < 4; ++ks) {
    bf16x8 af  = *(const bf16x8*)(abase + ks * 32);
    bf16x8 k0  = *(const bf16x8*)(wk + ks * 32);
    bf16x8 k1  = *(const bf16x8*)(wk + (size_t)16 * D + ks * 32);
    bf16x8 q0  = *(const bf16x8*)(wq + ks * 32);
    bf16x8 q1  = *(const bf16x8*)(wq + (size_t)16 * D + ks * 32);
    bf16x8 v0  = *(const bf16x8*)(wv + ks * 32);
    bf16x8 v1  = *(const bf16x8*)(wv + (size_t)16 * D + ks * 32);
    aK0 = __builtin_amdgcn_mfma_f32_16x16x32_bf16(af, k0, aK0, 0, 0, 0);
    aK1 = __builtin_amdgcn_mfma_f32_16x16x32_bf16(af, k1, aK1, 0, 0, 0);
    aQ0 = __builtin_amdgcn_mfma_f32_16x16x32_bf16(af, q0, aQ0, 0, 0, 0);
    aQ1 = __builtin_amdgcn_mfma_f32_16x16x32_bf16(af, q1, aQ1, 0, 0, 0);
    aV0 = __builtin_amdgcn_mfma_f32_16x16x32_bf16(af, v0, aV0, 0, 0, 0);
    aV1 = __builtin_amdgcn_mfma_f32_16x16x32_bf16(af, v1, aV1, 0, 0, 0);
  }

  int o = l & 15, kg4 = (l >> 4) * 4;
#pragma unroll
  for (int ct = 0; ct < 2; ++ct) {
    f32x4 aK = ct ? aK1 : aK0;
    f32x4 aQ = ct ? aQ1 : aQ0;
    f32x4 aV = ct ? aV1 : aV0;
    int col = w * 32 + ct * 16 + o;
#pragma unroll
    for (int r = 0; r < 4; ++r) {
      int nid = nid_s[kg4 + r];
      if (nid >= 0) {
        kmpk[(size_t)nid * D + col] =
            ((unsigned)f2bf(aV[r]) << 16) | (unsigned)f2bf(aK[r]);
        oqt[(size_t)nid * D + col] = aQ[r];
      }
    }
  }
}

// ---------- per-node softmax aggregation, no max-shift (|a| << 1, exp safe),
//            4-way unrolled, fully pipelined accumulation ----------
__global__ void k_agg(const int* __restrict__ esrc, const int* __restrict__ off,
                      const unsigned int* __restrict__ kmpk,
                      const float* __restrict__ qt,
                      float* __restrict__ hagg, int N) {
  int n = blockIdx.x;
  int j = threadIdx.x;  // 0..127
  float qv = qt[(size_t)n * D + j];
  int i0 = off[n], i1 = off[n + 1];
  float ssum = 0.f, acc = 0.f;
  int i = i0;
  for (; i + 4 <= i1; i += 4) {
    int s0 = esrc[i], s1 = esrc[i + 1], s2 = esrc[i + 2], s3 = esrc[i + 3];
    unsigned p0 = kmpk[(size_t)s0 * D + j];
    unsigned p1 = kmpk[(size_t)s1 * D + j];
    unsigned p2 = kmpk[(size_t)s2 * D + j];
    unsigned p3 = kmpk[(size_t)s3 * D + j];
    float kv0 = __uint_as_float(p0 << 16), mv0 = __uint_as_float(p0 & 0xffff0000u);
    float kv1 = __uint_as_float(p1 << 16), mv1 = __uint_as_float(p1 & 0xffff0000u);
    float kv2 = __uint_as_float(p2 << 16), mv2 = __uint_as_float(p2 & 0xffff0000u);
    float kv3 = __uint_as_float(p3 << 16), mv3 = __uint_as_float(p3 & 0xffff0000u);
    float a0 = kv0 * qv, a1 = kv1 * qv, a2 = kv2 * qv, a3 = kv3 * qv;
#pragma unroll
    for (int o = 8; o >= 1; o >>= 1) {
      a0 += __shfl_xor(a0, o);
      a1 += __shfl_xor(a1, o);
      a2 += __shfl_xor(a2, o);
      a3 += __shfl_xor(a3, o);
    }
    float w0 = __expf(a0), w1 = __expf(a1), w2 = __expf(a2), w3 = __expf(a3);
    ssum += (w0 + w1) + (w2 + w3);
    acc += (w0 * mv0 + w1 * mv1) + (w2 * mv2 + w3 * mv3);
  }
  for (; i < i1; ++i) {
    int sn = esrc[i];
    unsigned p = kmpk[(size_t)sn * D + j];
    float kv = __uint_as_float(p << 16), mv = __uint_as_float(p & 0xffff0000u);
    float a = kv * qv;
#pragma unroll
    for (int o = 8; o >= 1; o >>= 1) a += __shfl_xor(a, o);
    float wgt = __expf(a);
    ssum += wgt;
    acc += wgt * mv;
  }
  hagg[(size_t)n * D + j] = (ssum > 0.f) ? acc / ssum : 0.f;
}

// ---------- fp32 Wa GEMM, 16 nodes/block, 512 thr (4 node-groups x 4 nodes),
//            unroll-4 pipeline + x prefetch; skip/LN/residual/FiLM epilogue ----------
__global__ void __launch_bounds__(512)
k_out(const float* __restrict__ hagg, const int* __restrict__ pnid,
      const int* __restrict__ ntype, const float* __restrict__ Wa,
      const float* __restrict__ x, const float* __restrict__ skip,
      const float* __restrict__ ln_g, const float* __restrict__ ln_b,
      const float* __restrict__ gb, float* __restrict__ out) {
  int b = blockIdx.x, tid = threadIdx.x;
  int j = tid & 127, g = tid >> 7;  // g in {0..3}: nodes g*4 .. g*4+3
  __shared__ __align__(16) float hs[NBO][D];
  __shared__ int nid_s[NBO];
  __shared__ float red[8][4][2];  // [wave][local nn][s1,s2]
  if (tid < NBO) nid_s[tid] = pnid[b * NBO + tid];
  __syncthreads();
  for (int idx = tid; idx < NBO * D; idx += 512) {
    int nn = idx >> 7, col = idx & 127;
    int nid = nid_s[nn];
    hs[nn][col] = (nid >= 0) ? hagg[(size_t)nid * D + col] : 0.f;
  }
  __syncthreads();
  int tfirst = -1;
#pragma unroll
  for (int nn = 0; nn < NBO; ++nn) if (tfirst < 0 && nid_s[nn] >= 0) tfirst = ntype[nid_s[nn]];
  if (tfirst < 0) return;
  // prefetch epilogue x values: latency hides under the GEMM below
  float xpre[4];
#pragma unroll
  for (int nn = 0; nn < 4; ++nn) {
    int nid = nid_s[g * 4 + nn];
    xpre[nn] = (nid >= 0) ? x[(size_t)nid * D + j] : 0.f;
  }
  const float* wp = Wa + (size_t)tfirst * (D * D) + j;  // coalesced across j
  float acc[4];
#pragma unroll
  for (int nn = 0; nn < 4; ++nn) acc[nn] = 0.f;
#pragma unroll 4
  for (int d = 0; d < D; d += 4) {
    float w0 = wp[(size_t)d * D];
    float w1 = wp[(size_t)(d + 1) * D];
    float w2 = wp[(size_t)(d + 2) * D];
    float w3 = wp[(size_t)(d + 3) * D];
#pragma unroll
    for (int nn = 0; nn < 4; ++nn) {
      float4 h4 = *(const float4*)(&hs[g * 4 + nn][d]);  // ds_read_b128
      acc[nn] = fmaf(h4.x, w0, acc[nn]);
      acc[nn] = fmaf(h4.y, w1, acc[nn]);
      acc[nn] = fmaf(h4.z, w2, acc[nn]);
      acc[nn] = fmaf(h4.w, w3, acc[nn]);
    }
  }
  float alpha = 1.f / (1.f + __expf(-skip[tfirst]));
  int w = tid >> 6;  // 0..7
  float hv[4];
#pragma unroll
  for (int nn = 0; nn < 4; ++nn) {
    int nid = nid_s[g * 4 + nn];
    hv[nn] = (nid >= 0) ? (acc[nn] * alpha + xpre[nn] * (1.f - alpha)) : 0.f;
    float s1 = hv[nn], s2 = hv[nn] * hv[nn];
#pragma unroll
    for (int o = 1; o < 64; o <<= 1) {
      s1 += __shfl_xor(s1, o);
      s2 += __shfl_xor(s2, o);
    }
    if ((tid & 63) == 0) { red[w][nn][0] = s1; red[w][nn][1] = s2; }
  }
  __syncthreads();
  float gj = ln_g[j], bj = ln_b[j], gmj = gb[j], gbj = gb[D + j];
#pragma unroll
  for (int nn = 0; nn < 4; ++nn) {
    int nid = nid_s[g * 4 + nn];
    if (nid < 0) continue;
    float mu = (red[2 * g][nn][0] + red[2 * g + 1][nn][0]) * (1.f / D);
    float m2 = (red[2 * g][nn][1] + red[2 * g + 1][nn][1]) * (1.f / D);
    float var = m2 - mu * mu;
    float y = (hv[nn] - mu) * rsqrtf(var + 1e-5f) * gj + bj + xpre[nn];
    out[(size_t)nid * D + j] = gmj * y + gbj;
  }
}

extern "C" void kernel_launch(void* const* d_in, const int* in_sizes, int n_in,
                              void* d_out, int out_size, void* d_ws, size_t ws_size,
                              hipStream_t stream) {
  const float* x       = (const float*)d_in[0];
  const float* gc      = (const float*)d_in[1];
  const float* Wk      = (const float*)d_in[2];
  const float* Wq      = (const float*)d_in[3];
  const float* Wv      = (const float*)d_in[4];
  const float* rel_att = (const float*)d_in[5];
  const float* rel_msg = (const float*)d_in[6];
  const float* rel_pri = (const float*)d_in[7];
  const float* Wa      = (const float*)d_in[8];
  const float* skip    = (const float*)d_in[9];
  const float* ln_g    = (const float*)d_in[10];
  const float* ln_b    = (const float*)d_in[11];
  const float* fw      = (const float*)d_in[12];
  const float* fb      = (const float*)d_in[13];
  const int* ntype     = (const int*)d_in[14];
  const int* src       = (const int*)d_in[15];
  const int* dst       = (const int*)d_in[16];
  float* out = (float*)d_out;

  int N = in_sizes[0] / D;
  int C = in_sizes[1];
  int E = in_sizes[15];

  int gridP = (N + NB - 1) / NB + T;  // upper bound on padded 16-node tiles
  int P = gridP * NB;                 // padded node-list size
  int gridO = P / NBO;                // 16-node tiles

  float* ws = (float*)d_ws;
  size_t nD = (size_t)N * D;
  float* wqt   = ws;                                 // N*128 fp32 qt (scaled)
  float* whagg = wqt + nD;                           // N*128 fp32 h_agg
  float* wgb   = whagg + nD;                         // 256 gamma|beta
  unsigned int*   kmpk = (unsigned int*)(wgb + 256); // N*128 packed {k,mt} bf16
  unsigned short* xb   = (unsigned short*)(kmpk + nD);  // N*128 bf16 x
  unsigned short* Wt   = xb + nD;                    // 3*3*128*128 bf16 col-major
  int* deg    = (int*)(Wt + 9 * D * D);  // N  (zeroed: deg,cursor,tcnt,tcur)
  int* cursor = deg + N;                 // N
  int* tcnt   = cursor + N;              // T
  int* tcur   = tcnt + T;                // T
  int* off    = tcur + T;                // N+1
  int* toff   = off + N + 1;             // T+1
  int* esrc   = toff + T + 1;            // E  (CSR-ordered src values)
  int* pnid   = esrc + E;                // P  (memset 0xFF -> -1)

  (void)hipMemsetAsync(deg, 0, (size_t)(2 * N + 2 * T) * sizeof(int), stream);
  (void)hipMemsetAsync(pnid, 0xFF, (size_t)P * sizeof(int), stream);

  int mNE = (E > N) ? E : N;
  int n8 = (int)(nD / 8);
  int BE = (mNE + 1023) / 1024;
  int BX = (n8 + 255) / 256;
  k_prep<<<73 + BE + BX, 256, 0, stream>>>(dst, ntype, deg, tcnt, N, E,
                                           x, xb, n8, Wk, Wq, Wv, Wt,
                                           rel_att, rel_msg, rel_pri,
                                           gc, fw, fb, wgb, C, BE);
  k_scan<<<1, 1024, 0, stream>>>(deg, off, tcnt, toff, N, E);
  k_scatter<<<(mNE + 255) / 256, 256, 0, stream>>>(dst, src, ntype, off, toff,
                                                   cursor, tcur, esrc, pnid, N, E);
  k_proj_f<<<gridP, 256, 0, stream>>>(xb, pnid, ntype, Wt, kmpk, wqt);
  k_agg<<<N, D, 0, stream>>>(esrc, off, kmpk, wqt, whagg, N);
  k_out<<<gridO, 512, 0, stream>>>(whagg, pnid, ntype, Wa, x, skip, ln_g, ln_b,
                                   wgb, out);
}

// Round 23
// 156.308 us; speedup vs baseline: 1.3340x; 1.1066x over previous
//
#include <hip/hip_runtime.h>
#include <hip/hip_bf16.h>

constexpr int D  = 128;
constexpr int H  = 8;
constexpr int DH = 16;
constexpr int NB  = 16;  // nodes per MFMA tile / type-bucket alignment
constexpr int NBO = 16;  // nodes per k_out tile
constexpr int T  = 3;

typedef __attribute__((ext_vector_type(8))) short bf16x8;
typedef __attribute__((ext_vector_type(4))) float f32x4;

__device__ inline unsigned short f2bf(float f) {  // fp32 -> bf16 bits (RNE)
  unsigned u = __float_as_uint(f);
  unsigned r = u + 0x7fffu + ((u >> 16) & 1u);
  return (unsigned short)(r >> 16);
}

// ---------- fused prep. Block roles:
//   blk 0: FiLM
//   [1, 73): weight prep, 72 chunk-blocks = 9 matrices x 8 col-chunks.
//   [73, 73+BE): edge count + type hist, 4 edges/thread
//   [73+BE, ...): cast x -> bf16, 8 elems/thread ----------
__global__ void k_prep(const int* __restrict__ dst, const int* __restrict__ ntype,
                       int* __restrict__ deg, int* __restrict__ tcnt, int N, int E,
                       const float* __restrict__ x, unsigned short* __restrict__ xb,
                       int n8,
                       const float* __restrict__ Wk, const float* __restrict__ Wq,
                       const float* __restrict__ Wv, unsigned short* __restrict__ Wt,
                       const float* __restrict__ ra_, const float* __restrict__ rm_,
                       const float* __restrict__ rp,
                       const float* __restrict__ gc, const float* __restrict__ fw,
                       const float* __restrict__ fb, float* __restrict__ gb, int C,
                       int BE) {
  int blk = blockIdx.x, tid = threadIdx.x;
  if (blk == 0) {  // FiLM: gb[0:128]=gamma, gb[128:256]=beta (256 threads)
    float a0 = 0.f, a1 = 0.f, a2 = 0.f, a3 = 0.f;
    int c = 0;
    for (; c + 4 <= C; c += 4) {
      a0 += gc[c] * fw[c * 256 + tid];
      a1 += gc[c + 1] * fw[(c + 1) * 256 + tid];
      a2 += gc[c + 2] * fw[(c + 2) * 256 + tid];
      a3 += gc[c + 3] * fw[(c + 3) * 256 + tid];
    }
    float acc = fb[tid] + (a0 + a1) + (a2 + a3);
    for (; c < C; ++c) acc += gc[c] * fw[c * 256 + tid];
    gb[tid] = acc;
    return;
  }
  if (blk < 73) {  // weight prep chunk
    int b2 = blk - 1;              // 0..71
    int mt = b2 >> 3, chunk = b2 & 7;
    int m = mt / T, t = mt % T;
    unsigned short* o = Wt + ((size_t)m * T + t) * (D * D);
    if (m == 0) {
      const float* W = Wk + (size_t)t * (D * D);
#pragma unroll
      for (int k2 = 0; k2 < 8; ++k2) {
        int idx = k2 * 256 + tid;        // 0..2047
        int d = idx & 127, colL = idx >> 7;
        int col = chunk * 16 + colL;
        o[(size_t)col * D + d] = f2bf(W[(size_t)d * D + col]);
      }
      return;
    }
    __shared__ float cf[256];  // cf[dd*16+z]
    int h = chunk;
    if (m == 1) cf[tid] = ra_[h * 256 + tid];
    else        cf[tid] = rm_[h * 256 + (tid & 15) * 16 + (tid >> 4)];
    float scale = (m == 1) ? rp[h] * 0.25f : 1.f;
    __syncthreads();
    const float* W = (m == 1 ? Wq : Wv) + (size_t)t * (D * D);
#pragma unroll
    for (int k2 = 0; k2 < 8; ++k2) {
      int idx = k2 * 256 + tid;
      int c = idx & 127, colL = idx >> 7;   // consecutive tid -> consecutive c
      int col = chunk * 16 + colL, dd = colL;
      const float* wrow = W + (size_t)c * D + h * 16;
      float s = 0.f;
#pragma unroll
      for (int z = 0; z < 16; ++z) s += wrow[z] * cf[dd * 16 + z];
      o[(size_t)col * D + c] = f2bf(s * scale);
    }
    return;
  }
  if (blk < 73 + BE) {  // edge in-degree count + node type histogram (4/thread)
    int base = (blk - 73) * 1024;
    int lane = tid & 63;
#pragma unroll
    for (int k2 = 0; k2 < 4; ++k2) {
      int i = base + k2 * 256 + tid;
      if (i < E) atomicAdd(deg + dst[i], 1);
      int t = (i < N) ? ntype[i] : -1;
#pragma unroll
      for (int tt = 0; tt < T; ++tt) {
        unsigned long long mask = __ballot(t == tt);
        int cnt = __popcll(mask);
        if (cnt > 0 && lane == (__ffsll((long long)mask) - 1))
          atomicAdd(tcnt + tt, cnt);
      }
    }
    return;
  }
  // cast x -> bf16, 8 elems/thread
  int i = (blk - 73 - BE) * 256 + tid;
  if (i >= n8) return;
  const float4* p = (const float4*)(x + (size_t)i * 8);
  float4 a = p[0], b = p[1];
  ushort4 o0 = {f2bf(a.x), f2bf(a.y), f2bf(a.z), f2bf(a.w)};
  ushort4 o1 = {f2bf(b.x), f2bf(b.y), f2bf(b.z), f2bf(b.w)};
  ushort4* q = (ushort4*)(xb + (size_t)i * 8);
  q[0] = o0;
  q[1] = o1;
}

// ---------- parallel CSR allocation: per-wave scan of deg + one global
//            cursor bump per wave -> off[n] (bucket base). Buckets are NOT
//            node-ordered (unnecessary); per-bucket interval = [off, off+deg).
//            Also computes toff (3 values) on thread 0 of block 0. ----------
__global__ void k_alloc(const int* __restrict__ deg, int* __restrict__ off,
                        const int* __restrict__ tcnt, int* __restrict__ toff,
                        int* __restrict__ ecur, int N) {
  int i = blockIdx.x * blockDim.x + threadIdx.x;
  int lane = threadIdx.x & 63;
  if (blockIdx.x == 0 && threadIdx.x == 0) {
    toff[0] = 0;
    for (int t = 0; t < T; ++t) toff[t + 1] = toff[t] + ((tcnt[t] + NB - 1) / NB) * NB;
  }
  int v = (i < N) ? deg[i] : 0;
  int xs = v;  // inclusive scan within wave
#pragma unroll
  for (int o = 1; o < 64; o <<= 1) {
    int y = __shfl_up(xs, o);
    if (lane >= o) xs += y;
  }
  int wtotal = __shfl(xs, 63);
  int base = 0;
  if (lane == 63) base = atomicAdd(ecur, wtotal);
  base = __shfl(base, 63);
  if (i < N) off[i] = base + xs - v;
}

// ---------- scatter: edges -> CSR src values; nodes -> type buckets ----------
__global__ void k_scatter(const int* __restrict__ dst, const int* __restrict__ src,
                          const int* __restrict__ ntype,
                          const int* __restrict__ off, const int* __restrict__ toff,
                          int* __restrict__ cursor, int* __restrict__ tcur,
                          int* __restrict__ esrc, int* __restrict__ pnid, int N, int E) {
  int i = blockIdx.x * blockDim.x + threadIdx.x;
  if (i < E) {
    int d = dst[i];
    int pos = atomicAdd(cursor + d, 1);
    esrc[off[d] + pos] = src[i];
  }
  int t = (i < N) ? ntype[i] : -1;
  int lane = threadIdx.x & 63;
#pragma unroll
  for (int tt = 0; tt < T; ++tt) {
    unsigned long long mask = __ballot(t == tt);
    int cnt = __popcll(mask);
    if (cnt == 0) continue;
    int leader = __ffsll((long long)mask) - 1;
    int base = 0;
    if (lane == leader) base = atomicAdd(tcur + tt, cnt);
    base = __shfl(base, leader);
    if (t == tt) {
      int rank = __popcll(mask & ((1ull << lane) - 1ull));
      pnid[toff[tt] + base + rank] = i;
    }
  }
}

// ---------- fused MFMA projection: 16 nodes x 128 out x 3 matrices (k, qt, mt).
//            One A-fragment gather feeds 3 GEMMs; head transforms pre-folded
//            into Wq'/Wv'. 256 thr = 4 waves, wave owns 32 output cols.
//            A-frag: lane l elem i = A[l&15][(l>>4)*8+i]  (row-major)
//            B-frag: lane l elem i = B[(l>>4)*8+i][l&15]  (Wt col-major [c][k])
//            D: col = lane&15, row = (lane>>4)*4+reg  [verified r10/r14] ----------
__global__ void __launch_bounds__(256)
k_proj_f(const unsigned short* __restrict__ xb, const int* __restrict__ pnid,
         const int* __restrict__ ntype, const unsigned short* __restrict__ Wt,
         unsigned int* __restrict__ kmpk, float* __restrict__ oqt) {
  int b = blockIdx.x;
  int tid = threadIdx.x;
  int w = tid >> 6, l = tid & 63;
  __shared__ int nid_s[NB];
  if (tid < NB) nid_s[tid] = pnid[b * NB + tid];
  __syncthreads();
  int tfirst = -1;
#pragma unroll
  for (int nn = 0; nn < NB; ++nn) if (tfirst < 0 && nid_s[nn] >= 0) tfirst = ntype[nid_s[nn]];
  if (tfirst < 0) return;  // fully-padded block

  int arow = l & 15, kg = l >> 4;
  int anid = nid_s[arow];
  if (anid < 0) anid = 0;  // clamp: garbage rows never written back
  const unsigned short* abase = xb + (size_t)anid * D + kg * 8;
  int col0 = w * 32 + (l & 15);
  size_t coff = (size_t)col0 * D + kg * 8;
  const unsigned short* wk = Wt + ((size_t)0 * T + tfirst) * (D * D) + coff;
  const unsigned short* wq = Wt + ((size_t)1 * T + tfirst) * (D * D) + coff;
  const unsigned short* wv = Wt + ((size_t)2 * T + tfirst) * (D * D) + coff;
  f32x4 aK0 = {0.f, 0.f, 0.f, 0.f}, aK1 = aK0;
  f32x4 aQ0 = aK0, aQ1 = aK0, aV0 = aK0, aV1 = aK0;
#pragma unroll
  for (int ks = 0; ks < 4; ++ks) {
    bf16x8 af  = *(const bf16x8*)(abase + ks * 32);
    bf16x8 k0  = *(const bf16x8*)(wk + ks * 32);
    bf16x8 k1  = *(const bf16x8*)(wk + (size_t)16 * D + ks * 32);
    bf16x8 q0  = *(const bf16x8*)(wq + ks * 32);
    bf16x8 q1  = *(const bf16x8*)(wq + (size_t)16 * D + ks * 32);
    bf16x8 v0  = *(const bf16x8*)(wv + ks * 32);
    bf16x8 v1  = *(const bf16x8*)(wv + (size_t)16 * D + ks * 32);
    aK0 = __builtin_amdgcn_mfma_f32_16x16x32_bf16(af, k0, aK0, 0, 0, 0);
    aK1 = __builtin_amdgcn_mfma_f32_16x16x32_bf16(af, k1, aK1, 0, 0, 0);
    aQ0 = __builtin_amdgcn_mfma_f32_16x16x32_bf16(af, q0, aQ0, 0, 0, 0);
    aQ1 = __builtin_amdgcn_mfma_f32_16x16x32_bf16(af, q1, aQ1, 0, 0, 0);
    aV0 = __builtin_amdgcn_mfma_f32_16x16x32_bf16(af, v0, aV0, 0, 0, 0);
    aV1 = __builtin_amdgcn_mfma_f32_16x16x32_bf16(af, v1, aV1, 0, 0, 0);
  }

  int o = l & 15, kg4 = (l >> 4) * 4;
#pragma unroll
  for (int ct = 0; ct < 2; ++ct) {
    f32x4 aK = ct ? aK1 : aK0;
    f32x4 aQ = ct ? aQ1 : aQ0;
    f32x4 aV = ct ? aV1 : aV0;
    int col = w * 32 + ct * 16 + o;
#pragma unroll
    for (int r = 0; r < 4; ++r) {
      int nid = nid_s[kg4 + r];
      if (nid >= 0) {
        kmpk[(size_t)nid * D + col] =
            ((unsigned)f2bf(aV[r]) << 16) | (unsigned)f2bf(aK[r]);
        oqt[(size_t)nid * D + col] = aQ[r];
      }
    }
  }
}

// ---------- per-node softmax aggregation, no max-shift (|a| << 1, exp safe),
//            4-way unrolled, fully pipelined accumulation ----------
__global__ void k_agg(const int* __restrict__ esrc, const int* __restrict__ off,
                      const int* __restrict__ deg,
                      const unsigned int* __restrict__ kmpk,
                      const float* __restrict__ qt,
                      float* __restrict__ hagg, int N) {
  int n = blockIdx.x;
  int j = threadIdx.x;  // 0..127
  float qv = qt[(size_t)n * D + j];
  int i0 = off[n], i1 = i0 + deg[n];
  float ssum = 0.f, acc = 0.f;
  int i = i0;
  for (; i + 4 <= i1; i += 4) {
    int s0 = esrc[i], s1 = esrc[i + 1], s2 = esrc[i + 2], s3 = esrc[i + 3];
    unsigned p0 = kmpk[(size_t)s0 * D + j];
    unsigned p1 = kmpk[(size_t)s1 * D + j];
    unsigned p2 = kmpk[(size_t)s2 * D + j];
    unsigned p3 = kmpk[(size_t)s3 * D + j];
    float kv0 = __uint_as_float(p0 << 16), mv0 = __uint_as_float(p0 & 0xffff0000u);
    float kv1 = __uint_as_float(p1 << 16), mv1 = __uint_as_float(p1 & 0xffff0000u);
    float kv2 = __uint_as_float(p2 << 16), mv2 = __uint_as_float(p2 & 0xffff0000u);
    float kv3 = __uint_as_float(p3 << 16), mv3 = __uint_as_float(p3 & 0xffff0000u);
    float a0 = kv0 * qv, a1 = kv1 * qv, a2 = kv2 * qv, a3 = kv3 * qv;
#pragma unroll
    for (int o = 8; o >= 1; o >>= 1) {
      a0 += __shfl_xor(a0, o);
      a1 += __shfl_xor(a1, o);
      a2 += __shfl_xor(a2, o);
      a3 += __shfl_xor(a3, o);
    }
    float w0 = __expf(a0), w1 = __expf(a1), w2 = __expf(a2), w3 = __expf(a3);
    ssum += (w0 + w1) + (w2 + w3);
    acc += (w0 * mv0 + w1 * mv1) + (w2 * mv2 + w3 * mv3);
  }
  for (; i < i1; ++i) {
    int sn = esrc[i];
    unsigned p = kmpk[(size_t)sn * D + j];
    float kv = __uint_as_float(p << 16), mv = __uint_as_float(p & 0xffff0000u);
    float a = kv * qv;
#pragma unroll
    for (int o = 8; o >= 1; o >>= 1) a += __shfl_xor(a, o);
    float wgt = __expf(a);
    ssum += wgt;
    acc += wgt * mv;
  }
  hagg[(size_t)n * D + j] = (ssum > 0.f) ? acc / ssum : 0.f;
}

// ---------- fp32 Wa GEMM, 16 nodes/block, 512 thr (4 node-groups x 4 nodes),
//            unroll-4 pipeline + x prefetch; skip/LN/residual/FiLM epilogue ----------
__global__ void __launch_bounds__(512)
k_out(const float* __restrict__ hagg, const int* __restrict__ pnid,
      const int* __restrict__ ntype, const float* __restrict__ Wa,
      const float* __restrict__ x, const float* __restrict__ skip,
      const float* __restrict__ ln_g, const float* __restrict__ ln_b,
      const float* __restrict__ gb, float* __restrict__ out) {
  int b = blockIdx.x, tid = threadIdx.x;
  int j = tid & 127, g = tid >> 7;  // g in {0..3}: nodes g*4 .. g*4+3
  __shared__ __align__(16) float hs[NBO][D];
  __shared__ int nid_s[NBO];
  __shared__ float red[8][4][2];  // [wave][local nn][s1,s2]
  if (tid < NBO) nid_s[tid] = pnid[b * NBO + tid];
  __syncthreads();
  for (int idx = tid; idx < NBO * D; idx += 512) {
    int nn = idx >> 7, col = idx & 127;
    int nid = nid_s[nn];
    hs[nn][col] = (nid >= 0) ? hagg[(size_t)nid * D + col] : 0.f;
  }
  __syncthreads();
  int tfirst = -1;
#pragma unroll
  for (int nn = 0; nn < NBO; ++nn) if (tfirst < 0 && nid_s[nn] >= 0) tfirst = ntype[nid_s[nn]];
  if (tfirst < 0) return;
  // prefetch epilogue x values: latency hides under the GEMM below
  float xpre[4];
#pragma unroll
  for (int nn = 0; nn < 4; ++nn) {
    int nid = nid_s[g * 4 + nn];
    xpre[nn] = (nid >= 0) ? x[(size_t)nid * D + j] : 0.f;
  }
  const float* wp = Wa + (size_t)tfirst * (D * D) + j;  // coalesced across j
  float acc[4];
#pragma unroll
  for (int nn = 0; nn < 4; ++nn) acc[nn] = 0.f;
#pragma unroll 4
  for (int d = 0; d < D; d += 4) {
    float w0 = wp[(size_t)d * D];
    float w1 = wp[(size_t)(d + 1) * D];
    float w2 = wp[(size_t)(d + 2) * D];
    float w3 = wp[(size_t)(d + 3) * D];
#pragma unroll
    for (int nn = 0; nn < 4; ++nn) {
      float4 h4 = *(const float4*)(&hs[g * 4 + nn][d]);  // ds_read_b128
      acc[nn] = fmaf(h4.x, w0, acc[nn]);
      acc[nn] = fmaf(h4.y, w1, acc[nn]);
      acc[nn] = fmaf(h4.z, w2, acc[nn]);
      acc[nn] = fmaf(h4.w, w3, acc[nn]);
    }
  }
  float alpha = 1.f / (1.f + __expf(-skip[tfirst]));
  int w = tid >> 6;  // 0..7
  float hv[4];
#pragma unroll
  for (int nn = 0; nn < 4; ++nn) {
    int nid = nid_s[g * 4 + nn];
    hv[nn] = (nid >= 0) ? (acc[nn] * alpha + xpre[nn] * (1.f - alpha)) : 0.f;
    float s1 = hv[nn], s2 = hv[nn] * hv[nn];
#pragma unroll
    for (int o = 1; o < 64; o <<= 1) {
      s1 += __shfl_xor(s1, o);
      s2 += __shfl_xor(s2, o);
    }
    if ((tid & 63) == 0) { red[w][nn][0] = s1; red[w][nn][1] = s2; }
  }
  __syncthreads();
  float gj = ln_g[j], bj = ln_b[j], gmj = gb[j], gbj = gb[D + j];
#pragma unroll
  for (int nn = 0; nn < 4; ++nn) {
    int nid = nid_s[g * 4 + nn];
    if (nid < 0) continue;
    float mu = (red[2 * g][nn][0] + red[2 * g + 1][nn][0]) * (1.f / D);
    float m2 = (red[2 * g][nn][1] + red[2 * g + 1][nn][1]) * (1.f / D);
    float var = m2 - mu * mu;
    float y = (hv[nn] - mu) * rsqrtf(var + 1e-5f) * gj + bj + xpre[nn];
    out[(size_t)nid * D + j] = gmj * y + gbj;
  }
}

extern "C" void kernel_launch(void* const* d_in, const int* in_sizes, int n_in,
                              void* d_out, int out_size, void* d_ws, size_t ws_size,
                              hipStream_t stream) {
  const float* x       = (const float*)d_in[0];
  const float* gc      = (const float*)d_in[1];
  const float* Wk      = (const float*)d_in[2];
  const float* Wq      = (const float*)d_in[3];
  const float* Wv      = (const float*)d_in[4];
  const float* rel_att = (const float*)d_in[5];
  const float* rel_msg = (const float*)d_in[6];
  const float* rel_pri = (const float*)d_in[7];
  const float* Wa      = (const float*)d_in[8];
  const float* skip    = (const float*)d_in[9];
  const float* ln_g    = (const float*)d_in[10];
  const float* ln_b    = (const float*)d_in[11];
  const float* fw      = (const float*)d_in[12];
  const float* fb      = (const float*)d_in[13];
  const int* ntype     = (const int*)d_in[14];
  const int* src       = (const int*)d_in[15];
  const int* dst       = (const int*)d_in[16];
  float* out = (float*)d_out;

  int N = in_sizes[0] / D;
  int C = in_sizes[1];
  int E = in_sizes[15];

  int gridP = (N + NB - 1) / NB + T;  // upper bound on padded 16-node tiles
  int P = gridP * NB;                 // padded node-list size
  int gridO = P / NBO;                // 16-node tiles

  float* ws = (float*)d_ws;
  size_t nD = (size_t)N * D;
  float* wqt   = ws;                                 // N*128 fp32 qt (scaled)
  float* whagg = wqt + nD;                           // N*128 fp32 h_agg
  float* wgb   = whagg + nD;                         // 256 gamma|beta
  unsigned int*   kmpk = (unsigned int*)(wgb + 256); // N*128 packed {k,mt} bf16
  unsigned short* xb   = (unsigned short*)(kmpk + nD);  // N*128 bf16 x
  unsigned short* Wt   = xb + nD;                    // 3*3*128*128 bf16 col-major
  int* deg    = (int*)(Wt + 9 * D * D);  // N  (zeroed: deg,cursor,tcnt,tcur,ecur)
  int* cursor = deg + N;                 // N
  int* tcnt   = cursor + N;              // T
  int* tcur   = tcnt + T;                // T
  int* ecur   = tcur + T;                // 1   global edge cursor
  int* off    = ecur + 1;                // N   (bucket base per node)
  int* toff   = off + N;                 // T+1
  int* esrc   = toff + T + 1;            // E  (CSR-ordered src values)
  int* pnid   = esrc + E;                // P  (memset 0xFF -> -1)

  (void)hipMemsetAsync(deg, 0, (size_t)(2 * N + 2 * T + 1) * sizeof(int), stream);
  (void)hipMemsetAsync(pnid, 0xFF, (size_t)P * sizeof(int), stream);

  int mNE = (E > N) ? E : N;
  int n8 = (int)(nD / 8);
  int BE = (mNE + 1023) / 1024;
  int BX = (n8 + 255) / 256;
  k_prep<<<73 + BE + BX, 256, 0, stream>>>(dst, ntype, deg, tcnt, N, E,
                                           x, xb, n8, Wk, Wq, Wv, Wt,
                                           rel_att, rel_msg, rel_pri,
                                           gc, fw, fb, wgb, C, BE);
  k_alloc<<<(N + 255) / 256, 256, 0, stream>>>(deg, off, tcnt, toff, ecur, N);
  k_scatter<<<(mNE + 255) / 256, 256, 0, stream>>>(dst, src, ntype, off, toff,
                                                   cursor, tcur, esrc, pnid, N, E);
  k_proj_f<<<gridP, 256, 0, stream>>>(xb, pnid, ntype, Wt, kmpk, wqt);
  k_agg<<<N, D, 0, stream>>>(esrc, off, deg, kmpk, wqt, whagg, N);
  k_out<<<gridO, 512, 0, stream>>>(whagg, pnid, ntype, Wa, x, skip, ln_g, ln_b,
                                   wgb, out);
}

// Round 24
// 139.217 us; speedup vs baseline: 1.4978x; 1.1228x over previous
//
#include <hip/hip_runtime.h>
#include <hip/hip_bf16.h>

constexpr int D  = 128;
constexpr int H  = 8;
constexpr int DH = 16;
constexpr int NB  = 16;  // nodes per MFMA tile / type-bucket alignment
constexpr int NBO = 16;  // nodes per k_out tile
constexpr int T  = 3;

typedef __attribute__((ext_vector_type(8))) short bf16x8;
typedef __attribute__((ext_vector_type(4))) float f32x4;

__device__ inline unsigned short f2bf(float f) {  // fp32 -> bf16 bits (RNE)
  unsigned u = __float_as_uint(f);
  unsigned r = u + 0x7fffu + ((u >> 16) & 1u);
  return (unsigned short)(r >> 16);
}

// ---------- zero the int scratch region (replaces 2 hipMemsetAsync fills,
//            which cost ~42 us each in-graph). int4 stores, 16B-aligned. ----------
__global__ void k_zero(int4* __restrict__ p, int n4) {
  int i = blockIdx.x * blockDim.x + threadIdx.x;
  if (i < n4) p[i] = make_int4(0, 0, 0, 0);
}

// ---------- fused prep. Block roles:
//   blk 0: FiLM
//   [1, 73): weight prep, 72 chunk-blocks = 9 matrices x 8 col-chunks.
//   [73, 73+BE): edge count + type hist, 4 edges/thread
//   [73+BE, ...): cast x -> bf16, 8 elems/thread ----------
__global__ void k_prep(const int* __restrict__ dst, const int* __restrict__ ntype,
                       int* __restrict__ deg, int* __restrict__ tcnt, int N, int E,
                       const float* __restrict__ x, unsigned short* __restrict__ xb,
                       int n8,
                       const float* __restrict__ Wk, const float* __restrict__ Wq,
                       const float* __restrict__ Wv, unsigned short* __restrict__ Wt,
                       const float* __restrict__ ra_, const float* __restrict__ rm_,
                       const float* __restrict__ rp,
                       const float* __restrict__ gc, const float* __restrict__ fw,
                       const float* __restrict__ fb, float* __restrict__ gb, int C,
                       int BE) {
  int blk = blockIdx.x, tid = threadIdx.x;
  if (blk == 0) {  // FiLM: gb[0:128]=gamma, gb[128:256]=beta (256 threads)
    float a0 = 0.f, a1 = 0.f, a2 = 0.f, a3 = 0.f;
    int c = 0;
    for (; c + 4 <= C; c += 4) {
      a0 += gc[c] * fw[c * 256 + tid];
      a1 += gc[c + 1] * fw[(c + 1) * 256 + tid];
      a2 += gc[c + 2] * fw[(c + 2) * 256 + tid];
      a3 += gc[c + 3] * fw[(c + 3) * 256 + tid];
    }
    float acc = fb[tid] + (a0 + a1) + (a2 + a3);
    for (; c < C; ++c) acc += gc[c] * fw[c * 256 + tid];
    gb[tid] = acc;
    return;
  }
  if (blk < 73) {  // weight prep chunk
    int b2 = blk - 1;              // 0..71
    int mt = b2 >> 3, chunk = b2 & 7;
    int m = mt / T, t = mt % T;
    unsigned short* o = Wt + ((size_t)m * T + t) * (D * D);
    if (m == 0) {
      const float* W = Wk + (size_t)t * (D * D);
#pragma unroll
      for (int k2 = 0; k2 < 8; ++k2) {
        int idx = k2 * 256 + tid;        // 0..2047
        int d = idx & 127, colL = idx >> 7;
        int col = chunk * 16 + colL;
        o[(size_t)col * D + d] = f2bf(W[(size_t)d * D + col]);
      }
      return;
    }
    __shared__ float cf[256];  // cf[dd*16+z]
    int h = chunk;
    if (m == 1) cf[tid] = ra_[h * 256 + tid];
    else        cf[tid] = rm_[h * 256 + (tid & 15) * 16 + (tid >> 4)];
    float scale = (m == 1) ? rp[h] * 0.25f : 1.f;
    __syncthreads();
    const float* W = (m == 1 ? Wq : Wv) + (size_t)t * (D * D);
#pragma unroll
    for (int k2 = 0; k2 < 8; ++k2) {
      int idx = k2 * 256 + tid;
      int c = idx & 127, colL = idx >> 7;   // consecutive tid -> consecutive c
      int col = chunk * 16 + colL, dd = colL;
      const float* wrow = W + (size_t)c * D + h * 16;
      float s = 0.f;
#pragma unroll
      for (int z = 0; z < 16; ++z) s += wrow[z] * cf[dd * 16 + z];
      o[(size_t)col * D + c] = f2bf(s * scale);
    }
    return;
  }
  if (blk < 73 + BE) {  // edge in-degree count + node type histogram (4/thread)
    int base = (blk - 73) * 1024;
    int lane = tid & 63;
#pragma unroll
    for (int k2 = 0; k2 < 4; ++k2) {
      int i = base + k2 * 256 + tid;
      if (i < E) atomicAdd(deg + dst[i], 1);
      int t = (i < N) ? ntype[i] : -1;
#pragma unroll
      for (int tt = 0; tt < T; ++tt) {
        unsigned long long mask = __ballot(t == tt);
        int cnt = __popcll(mask);
        if (cnt > 0 && lane == (__ffsll((long long)mask) - 1))
          atomicAdd(tcnt + tt, cnt);
      }
    }
    return;
  }
  // cast x -> bf16, 8 elems/thread
  int i = (blk - 73 - BE) * 256 + tid;
  if (i >= n8) return;
  const float4* p = (const float4*)(x + (size_t)i * 8);
  float4 a = p[0], b = p[1];
  ushort4 o0 = {f2bf(a.x), f2bf(a.y), f2bf(a.z), f2bf(a.w)};
  ushort4 o1 = {f2bf(b.x), f2bf(b.y), f2bf(b.z), f2bf(b.w)};
  ushort4* q = (ushort4*)(xb + (size_t)i * 8);
  q[0] = o0;
  q[1] = o1;
}

// ---------- parallel CSR allocation: per-wave scan of deg + one global
//            cursor bump per wave -> off[n] (bucket base). Buckets are NOT
//            node-ordered (unnecessary); per-bucket interval = [off, off+deg).
//            Also computes toff (3 values) on thread 0 of block 0. ----------
__global__ void k_alloc(const int* __restrict__ deg, int* __restrict__ off,
                        const int* __restrict__ tcnt, int* __restrict__ toff,
                        int* __restrict__ ecur, int N) {
  int i = blockIdx.x * blockDim.x + threadIdx.x;
  int lane = threadIdx.x & 63;
  if (blockIdx.x == 0 && threadIdx.x == 0) {
    toff[0] = 0;
    for (int t = 0; t < T; ++t) toff[t + 1] = toff[t] + ((tcnt[t] + NB - 1) / NB) * NB;
  }
  int v = (i < N) ? deg[i] : 0;
  int xs = v;  // inclusive scan within wave
#pragma unroll
  for (int o = 1; o < 64; o <<= 1) {
    int y = __shfl_up(xs, o);
    if (lane >= o) xs += y;
  }
  int wtotal = __shfl(xs, 63);
  int base = 0;
  if (lane == 63) base = atomicAdd(ecur, wtotal);
  base = __shfl(base, 63);
  if (i < N) off[i] = base + xs - v;
}

// ---------- scatter: edges -> CSR src values; nodes -> type buckets.
//            pnid stores nid+1 (0 = empty pad slot, pre-zeroed). ----------
__global__ void k_scatter(const int* __restrict__ dst, const int* __restrict__ src,
                          const int* __restrict__ ntype,
                          const int* __restrict__ off, const int* __restrict__ toff,
                          int* __restrict__ cursor, int* __restrict__ tcur,
                          int* __restrict__ esrc, int* __restrict__ pnid, int N, int E) {
  int i = blockIdx.x * blockDim.x + threadIdx.x;
  if (i < E) {
    int d = dst[i];
    int pos = atomicAdd(cursor + d, 1);
    esrc[off[d] + pos] = src[i];
  }
  int t = (i < N) ? ntype[i] : -1;
  int lane = threadIdx.x & 63;
#pragma unroll
  for (int tt = 0; tt < T; ++tt) {
    unsigned long long mask = __ballot(t == tt);
    int cnt = __popcll(mask);
    if (cnt == 0) continue;
    int leader = __ffsll((long long)mask) - 1;
    int base = 0;
    if (lane == leader) base = atomicAdd(tcur + tt, cnt);
    base = __shfl(base, leader);
    if (t == tt) {
      int rank = __popcll(mask & ((1ull << lane) - 1ull));
      pnid[toff[tt] + base + rank] = i + 1;
    }
  }
}

// ---------- fused MFMA projection: 16 nodes x 128 out x 3 matrices (k, qt, mt).
//            One A-fragment gather feeds 3 GEMMs; head transforms pre-folded
//            into Wq'/Wv'. 256 thr = 4 waves, wave owns 32 output cols.
//            A-frag: lane l elem i = A[l&15][(l>>4)*8+i]  (row-major)
//            B-frag: lane l elem i = B[(l>>4)*8+i][l&15]  (Wt col-major [c][k])
//            D: col = lane&15, row = (lane>>4)*4+reg  [verified r10/r14] ----------
__global__ void __launch_bounds__(256)
k_proj_f(const unsigned short* __restrict__ xb, const int* __restrict__ pnid,
         const int* __restrict__ ntype, const unsigned short* __restrict__ Wt,
         unsigned int* __restrict__ kmpk, float* __restrict__ oqt) {
  int b = blockIdx.x;
  int tid = threadIdx.x;
  int w = tid >> 6, l = tid & 63;
  __shared__ int nid_s[NB];
  if (tid < NB) nid_s[tid] = pnid[b * NB + tid] - 1;  // 0 -> -1 (pad)
  __syncthreads();
  int tfirst = -1;
#pragma unroll
  for (int nn = 0; nn < NB; ++nn) if (tfirst < 0 && nid_s[nn] >= 0) tfirst = ntype[nid_s[nn]];
  if (tfirst < 0) return;  // fully-padded block

  int arow = l & 15, kg = l >> 4;
  int anid = nid_s[arow];
  if (anid < 0) anid = 0;  // clamp: garbage rows never written back
  const unsigned short* abase = xb + (size_t)anid * D + kg * 8;
  int col0 = w * 32 + (l & 15);
  size_t coff = (size_t)col0 * D + kg * 8;
  const unsigned short* wk = Wt + ((size_t)0 * T + tfirst) * (D * D) + coff;
  const unsigned short* wq = Wt + ((size_t)1 * T + tfirst) * (D * D) + coff;
  const unsigned short* wv = Wt + ((size_t)2 * T + tfirst) * (D * D) + coff;
  f32x4 aK0 = {0.f, 0.f, 0.f, 0.f}, aK1 = aK0;
  f32x4 aQ0 = aK0, aQ1 = aK0, aV0 = aK0, aV1 = aK0;
#pragma unroll
  for (int ks = 0; ks < 4; ++ks) {
    bf16x8 af  = *(const bf16x8*)(abase + ks * 32);
    bf16x8 k0  = *(const bf16x8*)(wk + ks * 32);
    bf16x8 k1  = *(const bf16x8*)(wk + (size_t)16 * D + ks * 32);
    bf16x8 q0  = *(const bf16x8*)(wq + ks * 32);
    bf16x8 q1  = *(const bf16x8*)(wq + (size_t)16 * D + ks * 32);
    bf16x8 v0  = *(const bf16x8*)(wv + ks * 32);
    bf16x8 v1  = *(const bf16x8*)(wv + (size_t)16 * D + ks * 32);
    aK0 = __builtin_amdgcn_mfma_f32_16x16x32_bf16(af, k0, aK0, 0, 0, 0);
    aK1 = __builtin_amdgcn_mfma_f32_16x16x32_bf16(af, k1, aK1, 0, 0, 0);
    aQ0 = __builtin_amdgcn_mfma_f32_16x16x32_bf16(af, q0, aQ0, 0, 0, 0);
    aQ1 = __builtin_amdgcn_mfma_f32_16x16x32_bf16(af, q1, aQ1, 0, 0, 0);
    aV0 = __builtin_amdgcn_mfma_f32_16x16x32_bf16(af, v0, aV0, 0, 0, 0);
    aV1 = __builtin_amdgcn_mfma_f32_16x16x32_bf16(af, v1, aV1, 0, 0, 0);
  }

  int o = l & 15, kg4 = (l >> 4) * 4;
#pragma unroll
  for (int ct = 0; ct < 2; ++ct) {
    f32x4 aK = ct ? aK1 : aK0;
    f32x4 aQ = ct ? aQ1 : aQ0;
    f32x4 aV = ct ? aV1 : aV0;
    int col = w * 32 + ct * 16 + o;
#pragma unroll
    for (int r = 0; r < 4; ++r) {
      int nid = nid_s[kg4 + r];
      if (nid >= 0) {
        kmpk[(size_t)nid * D + col] =
            ((unsigned)f2bf(aV[r]) << 16) | (unsigned)f2bf(aK[r]);
        oqt[(size_t)nid * D + col] = aQ[r];
      }
    }
  }
}

// ---------- per-node softmax aggregation, no max-shift (|a| << 1, exp safe),
//            4-way unrolled, fully pipelined accumulation ----------
__global__ void k_agg(const int* __restrict__ esrc, const int* __restrict__ off,
                      const int* __restrict__ deg,
                      const unsigned int* __restrict__ kmpk,
                      const float* __restrict__ qt,
                      float* __restrict__ hagg, int N) {
  int n = blockIdx.x;
  int j = threadIdx.x;  // 0..127
  float qv = qt[(size_t)n * D + j];
  int i0 = off[n], i1 = i0 + deg[n];
  float ssum = 0.f, acc = 0.f;
  int i = i0;
  for (; i + 4 <= i1; i += 4) {
    int s0 = esrc[i], s1 = esrc[i + 1], s2 = esrc[i + 2], s3 = esrc[i + 3];
    unsigned p0 = kmpk[(size_t)s0 * D + j];
    unsigned p1 = kmpk[(size_t)s1 * D + j];
    unsigned p2 = kmpk[(size_t)s2 * D + j];
    unsigned p3 = kmpk[(size_t)s3 * D + j];
    float kv0 = __uint_as_float(p0 << 16), mv0 = __uint_as_float(p0 & 0xffff0000u);
    float kv1 = __uint_as_float(p1 << 16), mv1 = __uint_as_float(p1 & 0xffff0000u);
    float kv2 = __uint_as_float(p2 << 16), mv2 = __uint_as_float(p2 & 0xffff0000u);
    float kv3 = __uint_as_float(p3 << 16), mv3 = __uint_as_float(p3 & 0xffff0000u);
    float a0 = kv0 * qv, a1 = kv1 * qv, a2 = kv2 * qv, a3 = kv3 * qv;
#pragma unroll
    for (int o = 8; o >= 1; o >>= 1) {
      a0 += __shfl_xor(a0, o);
      a1 += __shfl_xor(a1, o);
      a2 += __shfl_xor(a2, o);
      a3 += __shfl_xor(a3, o);
    }
    float w0 = __expf(a0), w1 = __expf(a1), w2 = __expf(a2), w3 = __expf(a3);
    ssum += (w0 + w1) + (w2 + w3);
    acc += (w0 * mv0 + w1 * mv1) + (w2 * mv2 + w3 * mv3);
  }
  for (; i < i1; ++i) {
    int sn = esrc[i];
    unsigned p = kmpk[(size_t)sn * D + j];
    float kv = __uint_as_float(p << 16), mv = __uint_as_float(p & 0xffff0000u);
    float a = kv * qv;
#pragma unroll
    for (int o = 8; o >= 1; o >>= 1) a += __shfl_xor(a, o);
    float wgt = __expf(a);
    ssum += wgt;
    acc += wgt * mv;
  }
  hagg[(size_t)n * D + j] = (ssum > 0.f) ? acc / ssum : 0.f;
}

// ---------- fp32 Wa GEMM, 16 nodes/block, 512 thr (4 node-groups x 4 nodes),
//            unroll-4 pipeline + x prefetch; skip/LN/residual/FiLM epilogue ----------
__global__ void __launch_bounds__(512)
k_out(const float* __restrict__ hagg, const int* __restrict__ pnid,
      const int* __restrict__ ntype, const float* __restrict__ Wa,
      const float* __restrict__ x, const float* __restrict__ skip,
      const float* __restrict__ ln_g, const float* __restrict__ ln_b,
      const float* __restrict__ gb, float* __restrict__ out) {
  int b = blockIdx.x, tid = threadIdx.x;
  int j = tid & 127, g = tid >> 7;  // g in {0..3}: nodes g*4 .. g*4+3
  __shared__ __align__(16) float hs[NBO][D];
  __shared__ int nid_s[NBO];
  __shared__ float red[8][4][2];  // [wave][local nn][s1,s2]
  if (tid < NBO) nid_s[tid] = pnid[b * NBO + tid] - 1;  // 0 -> -1 (pad)
  __syncthreads();
  for (int idx = tid; idx < NBO * D; idx += 512) {
    int nn = idx >> 7, col = idx & 127;
    int nid = nid_s[nn];
    hs[nn][col] = (nid >= 0) ? hagg[(size_t)nid * D + col] : 0.f;
  }
  __syncthreads();
  int tfirst = -1;
#pragma unroll
  for (int nn = 0; nn < NBO; ++nn) if (tfirst < 0 && nid_s[nn] >= 0) tfirst = ntype[nid_s[nn]];
  if (tfirst < 0) return;
  // prefetch epilogue x values: latency hides under the GEMM below
  float xpre[4];
#pragma unroll
  for (int nn = 0; nn < 4; ++nn) {
    int nid = nid_s[g * 4 + nn];
    xpre[nn] = (nid >= 0) ? x[(size_t)nid * D + j] : 0.f;
  }
  const float* wp = Wa + (size_t)tfirst * (D * D) + j;  // coalesced across j
  float acc[4];
#pragma unroll
  for (int nn = 0; nn < 4; ++nn) acc[nn] = 0.f;
#pragma unroll 4
  for (int d = 0; d < D; d += 4) {
    float w0 = wp[(size_t)d * D];
    float w1 = wp[(size_t)(d + 1) * D];
    float w2 = wp[(size_t)(d + 2) * D];
    float w3 = wp[(size_t)(d + 3) * D];
#pragma unroll
    for (int nn = 0; nn < 4; ++nn) {
      float4 h4 = *(const float4*)(&hs[g * 4 + nn][d]);  // ds_read_b128
      acc[nn] = fmaf(h4.x, w0, acc[nn]);
      acc[nn] = fmaf(h4.y, w1, acc[nn]);
      acc[nn] = fmaf(h4.z, w2, acc[nn]);
      acc[nn] = fmaf(h4.w, w3, acc[nn]);
    }
  }
  float alpha = 1.f / (1.f + __expf(-skip[tfirst]));
  int w = tid >> 6;  // 0..7
  float hv[4];
#pragma unroll
  for (int nn = 0; nn < 4; ++nn) {
    int nid = nid_s[g * 4 + nn];
    hv[nn] = (nid >= 0) ? (acc[nn] * alpha + xpre[nn] * (1.f - alpha)) : 0.f;
    float s1 = hv[nn], s2 = hv[nn] * hv[nn];
#pragma unroll
    for (int o = 1; o < 64; o <<= 1) {
      s1 += __shfl_xor(s1, o);
      s2 += __shfl_xor(s2, o);
    }
    if ((tid & 63) == 0) { red[w][nn][0] = s1; red[w][nn][1] = s2; }
  }
  __syncthreads();
  float gj = ln_g[j], bj = ln_b[j], gmj = gb[j], gbj = gb[D + j];
#pragma unroll
  for (int nn = 0; nn < 4; ++nn) {
    int nid = nid_s[g * 4 + nn];
    if (nid < 0) continue;
    float mu = (red[2 * g][nn][0] + red[2 * g + 1][nn][0]) * (1.f / D);
    float m2 = (red[2 * g][nn][1] + red[2 * g + 1][nn][1]) * (1.f / D);
    float var = m2 - mu * mu;
    float y = (hv[nn] - mu) * rsqrtf(var + 1e-5f) * gj + bj + xpre[nn];
    out[(size_t)nid * D + j] = gmj * y + gbj;
  }
}

extern "C" void kernel_launch(void* const* d_in, const int* in_sizes, int n_in,
                              void* d_out, int out_size, void* d_ws, size_t ws_size,
                              hipStream_t stream) {
  const float* x       = (const float*)d_in[0];
  const float* gc      = (const float*)d_in[1];
  const float* Wk      = (const float*)d_in[2];
  const float* Wq      = (const float*)d_in[3];
  const float* Wv      = (const float*)d_in[4];
  const float* rel_att = (const float*)d_in[5];
  const float* rel_msg = (const float*)d_in[6];
  const float* rel_pri = (const float*)d_in[7];
  const float* Wa      = (const float*)d_in[8];
  const float* skip    = (const float*)d_in[9];
  const float* ln_g    = (const float*)d_in[10];
  const float* ln_b    = (const float*)d_in[11];
  const float* fw      = (const float*)d_in[12];
  const float* fb      = (const float*)d_in[13];
  const int* ntype     = (const int*)d_in[14];
  const int* src       = (const int*)d_in[15];
  const int* dst       = (const int*)d_in[16];
  float* out = (float*)d_out;

  int N = in_sizes[0] / D;
  int C = in_sizes[1];
  int E = in_sizes[15];

  int gridP = (N + NB - 1) / NB + T;  // upper bound on padded 16-node tiles
  int P = gridP * NB;                 // padded node-list size
  int gridO = P / NBO;                // 16-node tiles

  float* ws = (float*)d_ws;
  size_t nD = (size_t)N * D;
  float* wqt   = ws;                                 // N*128 fp32 qt (scaled)
  float* whagg = wqt + nD;                           // N*128 fp32 h_agg
  float* wgb   = whagg + nD;                         // 256 gamma|beta
  unsigned int*   kmpk = (unsigned int*)(wgb + 256); // N*128 packed {k,mt} bf16
  unsigned short* xb   = (unsigned short*)(kmpk + nD);  // N*128 bf16 x
  unsigned short* Wt   = xb + nD;                    // 3*3*128*128 bf16 col-major
  // zeroed region (contiguous, 16B-aligned): deg,cursor,tcnt,tcur,ecur,pnid
  int* deg    = (int*)(Wt + 9 * D * D);  // N
  int* cursor = deg + N;                 // N
  int* tcnt   = cursor + N;              // T
  int* tcur   = tcnt + T;                // T
  int* ecur   = tcur + T;                // 1   global edge cursor
  int* pnid   = ecur + 1;                // P   (0 = empty; stores nid+1)
  // not zeroed (fully written before read):
  int* off    = pnid + P;                // N   (bucket base per node)
  int* toff   = off + N;                 // T+1
  int* esrc   = toff + T + 1;            // E   (CSR-ordered src values)

  int nzero = 2 * N + 2 * T + 1 + P;     // ints to zero
  int n4 = (nzero + 3) / 4;              // int4 count (may over-run into off: safe)

  int mNE = (E > N) ? E : N;
  int n8 = (int)(nD / 8);
  int BE = (mNE + 1023) / 1024;
  int BX = (n8 + 255) / 256;
  k_zero<<<(n4 + 255) / 256, 256, 0, stream>>>((int4*)deg, n4);
  k_prep<<<73 + BE + BX, 256, 0, stream>>>(dst, ntype, deg, tcnt, N, E,
                                           x, xb, n8, Wk, Wq, Wv, Wt,
                                           rel_att, rel_msg, rel_pri,
                                           gc, fw, fb, wgb, C, BE);
  k_alloc<<<(N + 255) / 256, 256, 0, stream>>>(deg, off, tcnt, toff, ecur, N);
  k_scatter<<<(mNE + 255) / 256, 256, 0, stream>>>(dst, src, ntype, off, toff,
                                                   cursor, tcur, esrc, pnid, N, E);
  k_proj_f<<<gridP, 256, 0, stream>>>(xb, pnid, ntype, Wt, kmpk, wqt);
  k_agg<<<N, D, 0, stream>>>(esrc, off, deg, kmpk, wqt, whagg, N);
  k_out<<<gridO, 512, 0, stream>>>(whagg, pnid, ntype, Wa, x, skip, ln_g, ln_b,
                                   wgb, out);
}